// Round 18
// baseline (89.741 us; speedup 1.0000x reference)
//
#include <hip/hip_runtime.h>

// Nearest-prototype argmin: N=500k, K=256, D=64, fp32.
// R18 = R17 with three serial-latency removals (numerics byte-identical,
// absmax=0 heritage R12-R17):
//  1. No atomic list: flag bit 31 in out (R5/R6-proven) + scan fixup that
//     stages mus in LDS (R13-proven). Kills the ~55%-of-iters contended
//     atomic+readback stall and the in-path memset dispatch.
//  2. Balanced merge: each wave merges/stores 16 of the 32 points.
//  3. Prefetch depth 2 (two static register sets, x2-unrolled loop; no
//     runtime-indexed arrays per rule #20): covers HBM-miss latency
//     (FETCH 63MB -> ~half of X misses L3).

#define DIM 64
#define NPROTO 256
#define NBLK 1024
#define MARGIN_ACC 0.017f

using f32x4 = __attribute__((ext_vector_type(4))) float;
using f16x8 = __attribute__((ext_vector_type(8))) _Float16;

__device__ __forceinline__ f16x8 cvt8(float4 a, float4 b) {
    f16x8 r;
    r[0] = (_Float16)a.x; r[1] = (_Float16)a.y;
    r[2] = (_Float16)a.z; r[3] = (_Float16)a.w;
    r[4] = (_Float16)b.x; r[5] = (_Float16)b.y;
    r[6] = (_Float16)b.z; r[7] = (_Float16)b.w;
    return r;
}

// barrier that does NOT drain vmcnt (R15-proven): prefetch stays in flight.
__device__ __forceinline__ void barrier_keep_vmcnt() {
    asm volatile("s_waitcnt lgkmcnt(0)" ::: "memory");
    __builtin_amdgcn_s_barrier();
    __builtin_amdgcn_sched_barrier(0);
}

// pack slot indices into acc's low 8 mantissa bits, top-2 tree, running max
#define PACK_TREE(acc, b1, b2)                                          \
    {                                                                   \
        float pv[4];                                                    \
        _Pragma("unroll")                                               \
        for (int r = 0; r < 4; ++r) {                                   \
            unsigned u = __float_as_uint(acc[r]);                       \
            u = (u & 0xFFFFFF00u) + (unsigned)(kofs - p * 16 - r);      \
            pv[r] = __uint_as_float(u);                                 \
        }                                                               \
        const float t1a = fmaxf(pv[0], pv[1]), t2a = fminf(pv[0], pv[1]);\
        const float t1b = fmaxf(pv[2], pv[3]), t2b = fminf(pv[2], pv[3]);\
        const float p1 = fmaxf(t1a, t1b);                               \
        const float p2 = fmaxf(fminf(t1a, t1b), fmaxf(t2a, t2b));       \
        const float nb2 = fmaxf(fminf(b1, p1), fmaxf(b2, p2));          \
        b1 = fmaxf(b1, p1);                                             \
        b2 = nb2;                                                       \
    }

// load one 32-point group's B-source into 8 named float4 regs
#define LOADX(gt, x0, x1, x2, x3, y0, y1, y2, y3)                       \
    {                                                                   \
        int rA_ = (gt) * 32 + lp;      rA_ = (rA_ < n) ? rA_ : (n - 1); \
        int rB_ = (gt) * 32 + 16 + lp; rB_ = (rB_ < n) ? rB_ : (n - 1); \
        const float* pA_ = X + (size_t)rA_ * DIM + lg * 8;              \
        const float* pB_ = X + (size_t)rB_ * DIM + lg * 8;              \
        x0 = *(const float4*)(pA_);      x1 = *(const float4*)(pA_ + 4);\
        x2 = *(const float4*)(pA_ + 32); x3 = *(const float4*)(pA_ + 36);\
        y0 = *(const float4*)(pB_);      y1 = *(const float4*)(pB_ + 4);\
        y2 = *(const float4*)(pB_ + 32); y3 = *(const float4*)(pB_ + 36);\
    }

// one 32-point iteration: consume the given reg set, immediately re-issue
// it for group `gnext` (depth-2 distance), compute, exchange, merge, store.
#define BODY(gcur, gnext, PAR, x0, x1, x2, x3, y0, y1, y2, y3)          \
    {                                                                   \
        const f16x8 bxA0 = cvt8(x0, x1), bxA1 = cvt8(x2, x3);           \
        const f16x8 bxB0 = cvt8(y0, y1), bxB1 = cvt8(y2, y3);           \
        LOADX(gnext, x0, x1, x2, x3, y0, y1, y2, y3)                    \
        float b1A = -3.4e38f, b2A = -3.4e38f;                           \
        float b1B = -3.4e38f, b2B = -3.4e38f;                           \
        _Pragma("unroll")                                               \
        for (int p = 0; p < 8; ++p) {                                   \
            const f32x4 seed = *(const f32x4*)&s_seed[sbase + p * 16];  \
            f32x4 accA = __builtin_amdgcn_mfma_f32_16x16x32_f16(        \
                ah[p][0], bxA0, seed, 0, 0, 0);                         \
            f32x4 accB = __builtin_amdgcn_mfma_f32_16x16x32_f16(        \
                ah[p][0], bxB0, seed, 0, 0, 0);                         \
            accA = __builtin_amdgcn_mfma_f32_16x16x32_f16(              \
                ah[p][1], bxA1, accA, 0, 0, 0);                         \
            accB = __builtin_amdgcn_mfma_f32_16x16x32_f16(              \
                ah[p][1], bxB1, accB, 0, 0, 0);                         \
            PACK_TREE(accA, b1A, b2A)                                   \
            PACK_TREE(accB, b1B, b2B)                                   \
        }                                                               \
        _Pragma("unroll")                                               \
        for (int m = 16; m <= 32; m <<= 1) {                            \
            const float o1A = __shfl_xor(b1A, m), o2A = __shfl_xor(b2A, m);\
            const float o1B = __shfl_xor(b1B, m), o2B = __shfl_xor(b2B, m);\
            const float n2A = fmaxf(fminf(b1A, o1A), fmaxf(b2A, o2A));  \
            const float n2B = fmaxf(fminf(b1B, o1B), fmaxf(b2B, o2B));  \
            b1A = fmaxf(b1A, o1A); b2A = n2A;                           \
            b1B = fmaxf(b1B, o1B); b2B = n2B;                           \
        }                                                               \
        /* exchange halves: w0 gives B-pairs (lanes 16-31), w1 gives */ \
        /* A-pairs (lanes 0-15); point of lane l (<32) is gcur*32+l  */ \
        if (w == 0 && l >= 16 && l < 32)                                \
            s_pair[PAR][0][l] = make_uint2(__float_as_uint(b1B),        \
                                           __float_as_uint(b2B));       \
        if (w == 1 && l < 16)                                           \
            s_pair[PAR][1][l] = make_uint2(__float_as_uint(b1A),        \
                                           __float_as_uint(b2A));       \
        barrier_keep_vmcnt();                                           \
        const bool mine = (w == 0) ? (l < 16) : (l >= 16 && l < 32);    \
        if (mine) {                                                     \
            float f1 = (l < 16) ? b1A : b1B;                            \
            float f2 = (l < 16) ? b2A : b2B;                            \
            const uint2 o = s_pair[PAR][1 - w][l];                      \
            const float o1 = __uint_as_float(o.x);                      \
            const float o2 = __uint_as_float(o.y);                      \
            const float nb2 = fmaxf(fminf(f1, o1), fmaxf(f2, o2));      \
            f1 = fmaxf(f1, o1);                                         \
            f2 = nb2;                                                   \
            const int i = (gcur) * 32 + l;                              \
            if (i < n) {                                                \
                const unsigned u1 = __float_as_uint(f1);                \
                const int k1 = 255 - (int)(u1 & 0xFFu);                 \
                const float v1 = __uint_as_float(u1 & 0xFFFFFF00u);     \
                const float v2 =                                        \
                    __uint_as_float(__float_as_uint(f2) & 0xFFFFFF00u); \
                const unsigned fb =                                     \
                    ((v1 - v2) < MARGIN_ACC) ? 0x80000000u : 0u;        \
                out[i] = (int)((unsigned)k1 | fb);                      \
            }                                                           \
        }                                                               \
    }

__attribute__((amdgpu_waves_per_eu(2, 4)))
__global__ void __launch_bounds__(128)
argmin_mfma_kernel(const float* __restrict__ X,
                   const float* __restrict__ mus,
                   int* __restrict__ out, int n) {
    __shared__ __align__(16) float s_seed[NPROTO];  // -0.5*musq
    __shared__ uint2 s_pair[2][2][32];              // [par][wave][point]

    const int tid = threadIdx.x;   // block = 128 = 2 waves
    const int w = tid >> 6;        // wave 0: protos 0-127, wave 1: 128-255
    const int l = tid & 63;
    const int lp = l & 15;         // A-row / B-col lane index
    const int lg = l >> 4;         // k-group

    // ---- A-frags: 128 protos x K64 fp16 (proven layout); seed table ----
    f16x8 ah[8][2];
#pragma unroll
    for (int p = 0; p < 8; ++p) {
        const float* src = mus + (size_t)(w * 128 + p * 16 + lp) * DIM + lg * 8;
        const float4 a = *(const float4*)(src);
        const float4 b = *(const float4*)(src + 4);
        const float4 c = *(const float4*)(src + 32);
        const float4 d = *(const float4*)(src + 36);
        ah[p][0] = cvt8(a, b);
        ah[p][1] = cvt8(c, d);
        float s = 0.f;
        s = fmaf(a.x, a.x, fmaf(a.y, a.y, fmaf(a.z, a.z, fmaf(a.w, a.w, s))));
        s = fmaf(b.x, b.x, fmaf(b.y, b.y, fmaf(b.z, b.z, fmaf(b.w, b.w, s))));
        s = fmaf(c.x, c.x, fmaf(c.y, c.y, fmaf(c.z, c.z, fmaf(c.w, c.w, s))));
        s = fmaf(d.x, d.x, fmaf(d.y, d.y, fmaf(d.z, d.z, fmaf(d.w, d.w, s))));
        s += __shfl_xor(s, 16);
        s += __shfl_xor(s, 32);
        if (lg == 0) s_seed[w * 128 + p * 16 + lp] = -0.5f * s;
    }
    __syncthreads();   // publish seed table (one-time)

    // ---- 32-point group range for this block ----
    const int ng2 = (n + 31) / 32;   // 15625
    const int q = ng2 / NBLK, rr = ng2 % NBLK;
    const int bid = blockIdx.x;
    const int g0 = bid * q + (bid < rr ? bid : rr);
    const int cnt = q + (bid < rr ? 1 : 0);
    const int glast = g0 + cnt - 1;

    const int kofs = 255 - w * 128 - lg * 4;   // packed value = 255 - k
    const int sbase = w * 128 + lg * 4;

    // depth-2 prefetch: set P holds g0, set Q holds g0+1
    float4 pa0, pa1, pa2, pa3, pb0, pb1, pb2, pb3;   // set P
    float4 qa0, qa1, qa2, qa3, qb0, qb1, qb2, qb3;   // set Q
    LOADX(g0, pa0, pa1, pa2, pa3, pb0, pb1, pb2, pb3)
    {
        const int g1 = (g0 + 1 < glast) ? (g0 + 1) : glast;
        LOADX(g1, qa0, qa1, qa2, qa3, qb0, qb1, qb2, qb3)
    }

    int it = 0;
    for (; it + 1 < cnt; it += 2) {
        const int gA = g0 + it;
        const int gB = g0 + it + 1;
        const int nA = (gA + 2 < glast) ? (gA + 2) : glast;
        const int nB = (gB + 2 < glast) ? (gB + 2) : glast;
        BODY(gA, nA, 0, pa0, pa1, pa2, pa3, pb0, pb1, pb2, pb3)
        BODY(gB, nB, 1, qa0, qa1, qa2, qa3, qb0, qb1, qb2, qb3)
    }
    if (it < cnt) {
        const int gA = g0 + it;
        BODY(gA, glast, 0, pa0, pa1, pa2, pa3, pb0, pb1, pb2, pb3)
    }
}

#define MSTRIDE 65   // padded row stride: bank (l+d)%32, 2 lanes/bank = free

// Scan fixup with LDS-staged mus: stage all mus (+msq, exact R2 4-stripe
// order) into LDS once per block; scan out[] for flag bit 31; recompute
// flagged points one per wave from LDS (R13-proven inner loop).
__global__ void __launch_bounds__(256)
fixup_scan_lds_kernel(const float* __restrict__ X,
                      const float* __restrict__ mus,
                      int* __restrict__ out, int n) {
    __shared__ float s_mu[NPROTO * MSTRIDE];  // 65 KB
    __shared__ float s_msq[NPROTO];

    const int tid = threadIdx.x;
    {
        const float4* mr = (const float4*)(mus + (size_t)tid * DIM);
        float q0 = 0.f, q1 = 0.f, q2 = 0.f, q3 = 0.f;
#pragma unroll
        for (int qq = 0; qq < 16; ++qq) {
            const float4 mv = mr[qq];
            const int base = tid * MSTRIDE + qq * 4;
            s_mu[base]     = mv.x;
            s_mu[base + 1] = mv.y;
            s_mu[base + 2] = mv.z;
            s_mu[base + 3] = mv.w;
            q0 = fmaf(mv.x, mv.x, q0);
            q1 = fmaf(mv.y, mv.y, q1);
            q2 = fmaf(mv.z, mv.z, q2);
            q3 = fmaf(mv.w, mv.w, q3);
        }
        s_msq[tid] = (q0 + q1) + (q2 + q3);
    }
    __syncthreads();

    const int l = tid & 63;
    const int gw = (int)((blockIdx.x * blockDim.x + tid) >> 6);
    const int NW = (int)((gridDim.x * blockDim.x) >> 6);
    const int chunk = (n + NW - 1) / NW;
    const int base = gw * chunk;
    const int end = (base + chunk < n) ? (base + chunk) : n;

    for (int s = base; s < end; s += 64) {
        const int i = s + l;
        const int v = (i < end) ? out[i] : 0;
        const bool flg = (i < end) && ((unsigned)v & 0x80000000u);
        unsigned long long m = __ballot(flg);
        while (m) {
            const int src = (int)__ffsll((unsigned long long)m) - 1;
            m &= m - 1;
            const int pt = __shfl(i, src);
            // exact-fp32 recompute from LDS (R13-proven)
            const float4* xr = (const float4*)(X + (size_t)pt * DIM);
            float4 xv[16];
            float a0 = 0.f, a1 = 0.f, a2 = 0.f, a3 = 0.f;
#pragma unroll
            for (int qq = 0; qq < 16; ++qq) {
                xv[qq] = xr[qq];
                a0 = fmaf(xv[qq].x, xv[qq].x, a0);
                a1 = fmaf(xv[qq].y, xv[qq].y, a1);
                a2 = fmaf(xv[qq].z, xv[qq].z, a2);
                a3 = fmaf(xv[qq].w, xv[qq].w, a3);
            }
            const float xsq = (a0 + a1) + (a2 + a3);
            float b1 = 3.4e38f;
            int k1 = 0;
#pragma unroll
            for (int e = 0; e < 4; ++e) {
                const int p = e * 64 + l;           // k ascending per lane
                const float* mr = &s_mu[p * MSTRIDE];
                float d0 = 0.f, d1 = 0.f, d2 = 0.f, d3 = 0.f;
#pragma unroll
                for (int qq = 0; qq < 16; ++qq) {
                    d0 = fmaf(mr[qq * 4],     xv[qq].x, d0);
                    d1 = fmaf(mr[qq * 4 + 1], xv[qq].y, d1);
                    d2 = fmaf(mr[qq * 4 + 2], xv[qq].z, d2);
                    d3 = fmaf(mr[qq * 4 + 3], xv[qq].w, d3);
                }
                const float dot = (d0 + d1) + (d2 + d3);
                const float dd = (xsq - 2.0f * dot) + s_msq[p];
                if (dd < b1) { b1 = dd; k1 = p; }   // strict <: first-min
            }
#pragma unroll
            for (int mm = 1; mm < 64; mm <<= 1) {
                const float ob = __shfl_xor(b1, mm);
                const int ok = __shfl_xor(k1, mm);
                if (ob < b1 || (ob == b1 && ok < k1)) { b1 = ob; k1 = ok; }
            }
            if (l == 0) out[pt] = k1;
        }
    }
}

extern "C" void kernel_launch(void* const* d_in, const int* in_sizes, int n_in,
                              void* d_out, int out_size, void* d_ws, size_t ws_size,
                              hipStream_t stream) {
    const float* X = (const float*)d_in[0];
    const float* mus = (const float*)d_in[1];
    int* out = (int*)d_out;
    const int n = in_sizes[0] / DIM;  // 500000

    argmin_mfma_kernel<<<NBLK, 128, 0, stream>>>(X, mus, out, n);
    fixup_scan_lds_kernel<<<512, 256, 0, stream>>>(X, mus, out, n);
}

// Round 19
// 81.222 us; speedup vs baseline: 1.1049x; 1.1049x over previous
//
#include <hip/hip_runtime.h>

// Nearest-prototype argmin: N=500k, K=256, D=64, fp32.
// R19 = recombination of proven-best halves:
//  - MAIN from R18: 2-wave proto-split, 32 pts/iter, balanced merge (each
//    wave stores 16), depth-2 prefetch (two static reg sets), LDS seed into
//    MFMA C, packed argmax, non-draining barrier. Main measured < 70us.
//  - FIXUP from R17/R13: compacted list (per-wave ballot + atomicAdd) +
//    LDS-staged exact-fp32 fixup (~4us). R18 proved the scan fixup costs
//    ~20us and the in-loop atomic costs ~nothing -> list restored.
// Numerics byte-identical (absmax=0 heritage R12-R18).

#define DIM 64
#define NPROTO 256
#define NBLK 1024
#define MARGIN_ACC 0.017f

using f32x4 = __attribute__((ext_vector_type(4))) float;
using f16x8 = __attribute__((ext_vector_type(8))) _Float16;

__device__ __forceinline__ f16x8 cvt8(float4 a, float4 b) {
    f16x8 r;
    r[0] = (_Float16)a.x; r[1] = (_Float16)a.y;
    r[2] = (_Float16)a.z; r[3] = (_Float16)a.w;
    r[4] = (_Float16)b.x; r[5] = (_Float16)b.y;
    r[6] = (_Float16)b.z; r[7] = (_Float16)b.w;
    return r;
}

// barrier that does NOT drain vmcnt (R15-proven): prefetch stays in flight.
__device__ __forceinline__ void barrier_keep_vmcnt() {
    asm volatile("s_waitcnt lgkmcnt(0)" ::: "memory");
    __builtin_amdgcn_s_barrier();
    __builtin_amdgcn_sched_barrier(0);
}

// pack slot indices into acc's low 8 mantissa bits, top-2 tree, running max
#define PACK_TREE(acc, b1, b2)                                          \
    {                                                                   \
        float pv[4];                                                    \
        _Pragma("unroll")                                               \
        for (int r = 0; r < 4; ++r) {                                   \
            unsigned u = __float_as_uint(acc[r]);                       \
            u = (u & 0xFFFFFF00u) + (unsigned)(kofs - p * 16 - r);      \
            pv[r] = __uint_as_float(u);                                 \
        }                                                               \
        const float t1a = fmaxf(pv[0], pv[1]), t2a = fminf(pv[0], pv[1]);\
        const float t1b = fmaxf(pv[2], pv[3]), t2b = fminf(pv[2], pv[3]);\
        const float p1 = fmaxf(t1a, t1b);                               \
        const float p2 = fmaxf(fminf(t1a, t1b), fmaxf(t2a, t2b));       \
        const float nb2 = fmaxf(fminf(b1, p1), fmaxf(b2, p2));          \
        b1 = fmaxf(b1, p1);                                             \
        b2 = nb2;                                                       \
    }

// load one 32-point group's B-source into 8 named float4 regs
#define LOADX(gt, x0, x1, x2, x3, y0, y1, y2, y3)                       \
    {                                                                   \
        int rA_ = (gt) * 32 + lp;      rA_ = (rA_ < n) ? rA_ : (n - 1); \
        int rB_ = (gt) * 32 + 16 + lp; rB_ = (rB_ < n) ? rB_ : (n - 1); \
        const float* pA_ = X + (size_t)rA_ * DIM + lg * 8;              \
        const float* pB_ = X + (size_t)rB_ * DIM + lg * 8;              \
        x0 = *(const float4*)(pA_);      x1 = *(const float4*)(pA_ + 4);\
        x2 = *(const float4*)(pA_ + 32); x3 = *(const float4*)(pA_ + 36);\
        y0 = *(const float4*)(pB_);      y1 = *(const float4*)(pB_ + 4);\
        y2 = *(const float4*)(pB_ + 32); y3 = *(const float4*)(pB_ + 36);\
    }

// one 32-point iteration: consume the given reg set, immediately re-issue
// it for group `gnext` (depth-2 distance), compute, exchange, merge, store,
// append flagged points to the ws list (per-wave ballot, one atomic).
#define BODY(gcur, gnext, PAR, x0, x1, x2, x3, y0, y1, y2, y3)          \
    {                                                                   \
        const f16x8 bxA0 = cvt8(x0, x1), bxA1 = cvt8(x2, x3);           \
        const f16x8 bxB0 = cvt8(y0, y1), bxB1 = cvt8(y2, y3);           \
        LOADX(gnext, x0, x1, x2, x3, y0, y1, y2, y3)                    \
        float b1A = -3.4e38f, b2A = -3.4e38f;                           \
        float b1B = -3.4e38f, b2B = -3.4e38f;                           \
        _Pragma("unroll")                                               \
        for (int p = 0; p < 8; ++p) {                                   \
            const f32x4 seed = *(const f32x4*)&s_seed[sbase + p * 16];  \
            f32x4 accA = __builtin_amdgcn_mfma_f32_16x16x32_f16(        \
                ah[p][0], bxA0, seed, 0, 0, 0);                         \
            f32x4 accB = __builtin_amdgcn_mfma_f32_16x16x32_f16(        \
                ah[p][0], bxB0, seed, 0, 0, 0);                         \
            accA = __builtin_amdgcn_mfma_f32_16x16x32_f16(              \
                ah[p][1], bxA1, accA, 0, 0, 0);                         \
            accB = __builtin_amdgcn_mfma_f32_16x16x32_f16(              \
                ah[p][1], bxB1, accB, 0, 0, 0);                         \
            PACK_TREE(accA, b1A, b2A)                                   \
            PACK_TREE(accB, b1B, b2B)                                   \
        }                                                               \
        _Pragma("unroll")                                               \
        for (int m = 16; m <= 32; m <<= 1) {                            \
            const float o1A = __shfl_xor(b1A, m), o2A = __shfl_xor(b2A, m);\
            const float o1B = __shfl_xor(b1B, m), o2B = __shfl_xor(b2B, m);\
            const float n2A = fmaxf(fminf(b1A, o1A), fmaxf(b2A, o2A));  \
            const float n2B = fmaxf(fminf(b1B, o1B), fmaxf(b2B, o2B));  \
            b1A = fmaxf(b1A, o1A); b2A = n2A;                           \
            b1B = fmaxf(b1B, o1B); b2B = n2B;                           \
        }                                                               \
        /* exchange halves: w0 gives B-pairs (lanes 16-31), w1 gives */ \
        /* A-pairs (lanes 0-15); point of lane l (<32) is gcur*32+l  */ \
        if (w == 0 && l >= 16 && l < 32)                                \
            s_pair[PAR][0][l] = make_uint2(__float_as_uint(b1B),        \
                                           __float_as_uint(b2B));       \
        if (w == 1 && l < 16)                                           \
            s_pair[PAR][1][l] = make_uint2(__float_as_uint(b1A),        \
                                           __float_as_uint(b2A));       \
        barrier_keep_vmcnt();                                           \
        const bool mine = (w == 0) ? (l < 16) : (l >= 16 && l < 32);    \
        bool fl = false;                                                \
        const int i = (gcur) * 32 + l;                                  \
        if (mine && i < n) {                                            \
            float f1 = (l < 16) ? b1A : b1B;                            \
            float f2 = (l < 16) ? b2A : b2B;                            \
            const uint2 o = s_pair[PAR][1 - w][l];                      \
            const float o1 = __uint_as_float(o.x);                      \
            const float o2 = __uint_as_float(o.y);                      \
            const float nb2 = fmaxf(fminf(f1, o1), fmaxf(f2, o2));      \
            f1 = fmaxf(f1, o1);                                         \
            f2 = nb2;                                                   \
            const unsigned u1 = __float_as_uint(f1);                    \
            const int k1 = 255 - (int)(u1 & 0xFFu);                     \
            const float v1 = __uint_as_float(u1 & 0xFFFFFF00u);         \
            const float v2 =                                            \
                __uint_as_float(__float_as_uint(f2) & 0xFFFFFF00u);     \
            const bool close = (v1 - v2) < MARGIN_ACC;                  \
            if (use_list) {                                             \
                out[i] = k1;                                            \
                fl = close;                                             \
            } else {                                                    \
                out[i] = (int)((unsigned)k1 |                           \
                               (close ? 0x80000000u : 0u));             \
            }                                                           \
        }                                                               \
        if (use_list) {                                                 \
            const unsigned long long mask = __ballot(fl);               \
            if (mask) {                                                 \
                unsigned base = 0;                                      \
                if (l == 0)                                             \
                    base = atomicAdd(ws_count,                          \
                                     (unsigned)__popcll(mask));         \
                base = __shfl(base, 0);                                 \
                if (fl)                                                 \
                    ws_list[base +                                      \
                            __popcll(mask & ((1ull << l) - 1))] = i;    \
            }                                                           \
        }                                                               \
    }

__attribute__((amdgpu_waves_per_eu(2, 4)))
__global__ void __launch_bounds__(128)
argmin_mfma_kernel(const float* __restrict__ X,
                   const float* __restrict__ mus,
                   int* __restrict__ out,
                   unsigned* __restrict__ ws_count,
                   int* __restrict__ ws_list,
                   int use_list, int n) {
    __shared__ __align__(16) float s_seed[NPROTO];  // -0.5*musq
    __shared__ uint2 s_pair[2][2][32];              // [par][wave][point]

    const int tid = threadIdx.x;   // block = 128 = 2 waves
    const int w = tid >> 6;        // wave 0: protos 0-127, wave 1: 128-255
    const int l = tid & 63;
    const int lp = l & 15;         // A-row / B-col lane index
    const int lg = l >> 4;         // k-group

    // ---- A-frags: 128 protos x K64 fp16 (proven layout); seed table ----
    f16x8 ah[8][2];
#pragma unroll
    for (int p = 0; p < 8; ++p) {
        const float* src = mus + (size_t)(w * 128 + p * 16 + lp) * DIM + lg * 8;
        const float4 a = *(const float4*)(src);
        const float4 b = *(const float4*)(src + 4);
        const float4 c = *(const float4*)(src + 32);
        const float4 d = *(const float4*)(src + 36);
        ah[p][0] = cvt8(a, b);
        ah[p][1] = cvt8(c, d);
        float s = 0.f;
        s = fmaf(a.x, a.x, fmaf(a.y, a.y, fmaf(a.z, a.z, fmaf(a.w, a.w, s))));
        s = fmaf(b.x, b.x, fmaf(b.y, b.y, fmaf(b.z, b.z, fmaf(b.w, b.w, s))));
        s = fmaf(c.x, c.x, fmaf(c.y, c.y, fmaf(c.z, c.z, fmaf(c.w, c.w, s))));
        s = fmaf(d.x, d.x, fmaf(d.y, d.y, fmaf(d.z, d.z, fmaf(d.w, d.w, s))));
        s += __shfl_xor(s, 16);
        s += __shfl_xor(s, 32);
        if (lg == 0) s_seed[w * 128 + p * 16 + lp] = -0.5f * s;
    }
    __syncthreads();   // publish seed table (one-time)

    // ---- 32-point group range for this block ----
    const int ng2 = (n + 31) / 32;   // 15625
    const int q = ng2 / NBLK, rr = ng2 % NBLK;
    const int bid = blockIdx.x;
    const int g0 = bid * q + (bid < rr ? bid : rr);
    const int cnt = q + (bid < rr ? 1 : 0);
    const int glast = g0 + cnt - 1;

    const int kofs = 255 - w * 128 - lg * 4;   // packed value = 255 - k
    const int sbase = w * 128 + lg * 4;

    // depth-2 prefetch: set P holds g0, set Q holds g0+1
    float4 pa0, pa1, pa2, pa3, pb0, pb1, pb2, pb3;   // set P
    float4 qa0, qa1, qa2, qa3, qb0, qb1, qb2, qb3;   // set Q
    LOADX(g0, pa0, pa1, pa2, pa3, pb0, pb1, pb2, pb3)
    {
        const int g1 = (g0 + 1 < glast) ? (g0 + 1) : glast;
        LOADX(g1, qa0, qa1, qa2, qa3, qb0, qb1, qb2, qb3)
    }

    int it = 0;
    for (; it + 1 < cnt; it += 2) {
        const int gA = g0 + it;
        const int gB = g0 + it + 1;
        const int nA = (gA + 2 < glast) ? (gA + 2) : glast;
        const int nB = (gB + 2 < glast) ? (gB + 2) : glast;
        BODY(gA, nA, 0, pa0, pa1, pa2, pa3, pb0, pb1, pb2, pb3)
        BODY(gB, nB, 1, qa0, qa1, qa2, qa3, qb0, qb1, qb2, qb3)
    }
    if (it < cnt) {
        const int gA = g0 + it;
        BODY(gA, glast, 0, pa0, pa1, pa2, pa3, pb0, pb1, pb2, pb3)
    }
}

#define MSTRIDE 65   // padded row stride: bank (l+d)%32, 2 lanes/bank = free

// LDS-staged exact-fp32 fixup over the compacted list (R13-proven): stage
// all mus (+msq, exact R2 4-stripe order) into LDS once per block; one
// point per wave, grid-stride over the list.
__global__ void __launch_bounds__(256)
fixup_lds_kernel(const float* __restrict__ X, const float* __restrict__ mus,
                 const unsigned* __restrict__ ws_count,
                 const int* __restrict__ ws_list, int* __restrict__ out) {
    __shared__ float s_mu[NPROTO * MSTRIDE];  // 65 KB
    __shared__ float s_msq[NPROTO];

    const int tid = threadIdx.x;
    {
        const float4* mr = (const float4*)(mus + (size_t)tid * DIM);
        float q0 = 0.f, q1 = 0.f, q2 = 0.f, q3 = 0.f;
#pragma unroll
        for (int qq = 0; qq < 16; ++qq) {
            const float4 mv = mr[qq];
            const int base = tid * MSTRIDE + qq * 4;
            s_mu[base]     = mv.x;
            s_mu[base + 1] = mv.y;
            s_mu[base + 2] = mv.z;
            s_mu[base + 3] = mv.w;
            q0 = fmaf(mv.x, mv.x, q0);
            q1 = fmaf(mv.y, mv.y, q1);
            q2 = fmaf(mv.z, mv.z, q2);
            q3 = fmaf(mv.w, mv.w, q3);
        }
        s_msq[tid] = (q0 + q1) + (q2 + q3);
    }
    __syncthreads();

    const int l = tid & 63;
    const int gw = (int)((blockIdx.x * blockDim.x + tid) >> 6);
    const int NW = (int)((gridDim.x * blockDim.x) >> 6);
    const int nf = (int)*ws_count;

    for (int j = gw; j < nf; j += NW) {
        const int pt = ws_list[j];
        const float4* xr = (const float4*)(X + (size_t)pt * DIM);
        float4 xv[16];
        float a0 = 0.f, a1 = 0.f, a2 = 0.f, a3 = 0.f;
#pragma unroll
        for (int qq = 0; qq < 16; ++qq) {
            xv[qq] = xr[qq];
            a0 = fmaf(xv[qq].x, xv[qq].x, a0);
            a1 = fmaf(xv[qq].y, xv[qq].y, a1);
            a2 = fmaf(xv[qq].z, xv[qq].z, a2);
            a3 = fmaf(xv[qq].w, xv[qq].w, a3);
        }
        const float xsq = (a0 + a1) + (a2 + a3);
        float b1 = 3.4e38f;
        int k1 = 0;
#pragma unroll
        for (int e = 0; e < 4; ++e) {
            const int p = e * 64 + l;           // k ascending per lane
            const float* mr = &s_mu[p * MSTRIDE];
            float d0 = 0.f, d1 = 0.f, d2 = 0.f, d3 = 0.f;
#pragma unroll
            for (int qq = 0; qq < 16; ++qq) {
                d0 = fmaf(mr[qq * 4],     xv[qq].x, d0);
                d1 = fmaf(mr[qq * 4 + 1], xv[qq].y, d1);
                d2 = fmaf(mr[qq * 4 + 2], xv[qq].z, d2);
                d3 = fmaf(mr[qq * 4 + 3], xv[qq].w, d3);
            }
            const float dot = (d0 + d1) + (d2 + d3);
            const float dd = (xsq - 2.0f * dot) + s_msq[p];
            if (dd < b1) { b1 = dd; k1 = p; }   // strict <: first-min
        }
#pragma unroll
        for (int mm = 1; mm < 64; mm <<= 1) {
            const float ob = __shfl_xor(b1, mm);
            const int ok = __shfl_xor(k1, mm);
            if (ob < b1 || (ob == b1 && ok < k1)) { b1 = ob; k1 = ok; }
        }
        if (l == 0) out[pt] = k1;
    }
}

// Fallback scan fixup with LDS-staged mus (used only if ws too small).
__global__ void __launch_bounds__(256)
fixup_scan_lds_kernel(const float* __restrict__ X,
                      const float* __restrict__ mus,
                      int* __restrict__ out, int n) {
    __shared__ float s_mu[NPROTO * MSTRIDE];  // 65 KB
    __shared__ float s_msq[NPROTO];

    const int tid = threadIdx.x;
    {
        const float4* mr = (const float4*)(mus + (size_t)tid * DIM);
        float q0 = 0.f, q1 = 0.f, q2 = 0.f, q3 = 0.f;
#pragma unroll
        for (int qq = 0; qq < 16; ++qq) {
            const float4 mv = mr[qq];
            const int base = tid * MSTRIDE + qq * 4;
            s_mu[base]     = mv.x;
            s_mu[base + 1] = mv.y;
            s_mu[base + 2] = mv.z;
            s_mu[base + 3] = mv.w;
            q0 = fmaf(mv.x, mv.x, q0);
            q1 = fmaf(mv.y, mv.y, q1);
            q2 = fmaf(mv.z, mv.z, q2);
            q3 = fmaf(mv.w, mv.w, q3);
        }
        s_msq[tid] = (q0 + q1) + (q2 + q3);
    }
    __syncthreads();

    const int l = tid & 63;
    const int gw = (int)((blockIdx.x * blockDim.x + tid) >> 6);
    const int NW = (int)((gridDim.x * blockDim.x) >> 6);
    const int chunk = (n + NW - 1) / NW;
    const int base = gw * chunk;
    const int end = (base + chunk < n) ? (base + chunk) : n;

    for (int s = base; s < end; s += 64) {
        const int i = s + l;
        const int v = (i < end) ? out[i] : 0;
        const bool flg = (i < end) && ((unsigned)v & 0x80000000u);
        unsigned long long m = __ballot(flg);
        while (m) {
            const int src = (int)__ffsll((unsigned long long)m) - 1;
            m &= m - 1;
            const int pt = __shfl(i, src);
            const float4* xr = (const float4*)(X + (size_t)pt * DIM);
            float4 xv[16];
            float a0 = 0.f, a1 = 0.f, a2 = 0.f, a3 = 0.f;
#pragma unroll
            for (int qq = 0; qq < 16; ++qq) {
                xv[qq] = xr[qq];
                a0 = fmaf(xv[qq].x, xv[qq].x, a0);
                a1 = fmaf(xv[qq].y, xv[qq].y, a1);
                a2 = fmaf(xv[qq].z, xv[qq].z, a2);
                a3 = fmaf(xv[qq].w, xv[qq].w, a3);
            }
            const float xsq = (a0 + a1) + (a2 + a3);
            float b1 = 3.4e38f;
            int k1 = 0;
#pragma unroll
            for (int e = 0; e < 4; ++e) {
                const int p = e * 64 + l;
                const float* mr = &s_mu[p * MSTRIDE];
                float d0 = 0.f, d1 = 0.f, d2 = 0.f, d3 = 0.f;
#pragma unroll
                for (int qq = 0; qq < 16; ++qq) {
                    d0 = fmaf(mr[qq * 4],     xv[qq].x, d0);
                    d1 = fmaf(mr[qq * 4 + 1], xv[qq].y, d1);
                    d2 = fmaf(mr[qq * 4 + 2], xv[qq].z, d2);
                    d3 = fmaf(mr[qq * 4 + 3], xv[qq].w, d3);
                }
                const float dot = (d0 + d1) + (d2 + d3);
                const float dd = (xsq - 2.0f * dot) + s_msq[p];
                if (dd < b1) { b1 = dd; k1 = p; }
            }
#pragma unroll
            for (int mm = 1; mm < 64; mm <<= 1) {
                const float ob = __shfl_xor(b1, mm);
                const int ok = __shfl_xor(k1, mm);
                if (ob < b1 || (ob == b1 && ok < k1)) { b1 = ob; k1 = ok; }
            }
            if (l == 0) out[pt] = k1;
        }
    }
}

extern "C" void kernel_launch(void* const* d_in, const int* in_sizes, int n_in,
                              void* d_out, int out_size, void* d_ws, size_t ws_size,
                              hipStream_t stream) {
    const float* X = (const float*)d_in[0];
    const float* mus = (const float*)d_in[1];
    int* out = (int*)d_out;
    const int n = in_sizes[0] / DIM;  // 500000

    unsigned* ws_count = (unsigned*)d_ws;
    int* ws_list = (int*)((char*)d_ws + 16);
    const int use_list = (ws_size >= 16 + (size_t)n * 4) ? 1 : 0;

    if (use_list) {
        hipMemsetAsync(d_ws, 0, 16, stream);  // reset append counter
    }

    argmin_mfma_kernel<<<NBLK, 128, 0, stream>>>(X, mus, out, ws_count,
                                                 ws_list, use_list, n);
    if (use_list) {
        fixup_lds_kernel<<<512, 256, 0, stream>>>(X, mus, ws_count, ws_list,
                                                  out);
    } else {
        fixup_scan_lds_kernel<<<512, 256, 0, stream>>>(X, mus, out, n);
    }
}